// Round 7
// baseline (131.093 us; speedup 1.0000x reference)
//
#include <hip/hip_runtime.h>
#include <hip/hip_bf16.h>
#include <math.h>

// Contrastive (NT-Xent-like) loss over x[16384][64] fp32.
//   x_hat = sqrt(2*log2e) * x / ||x||   (so exp(sim/T) = exp2(x_hat_i.x_hat_j))
//   den[j] = sum_i exp2(x_hat_i . x_hat_j) - e^2
//   num[j] = exp2(x_hat_{j^1} . x_hat_j)
//   out = -log( mean_j num[j] / den[j] )
//
// Round 21: r20 post-mortem — 256x256 clean (no spill) but den 57 > r13's
// 45.8: 68 KB LDS + 172 VGPR -> 8 waves/CU, below the ~12-waves knee
// (r14: 12->16 no gain; r16/r20: 12->8 costs 2-11 us). Four structures agree:
// den ~46 us at 12 waves/CU, VALU-issue-bound at 57% with exp2 ~14 us
// irreducible; the missing 43% is whole-block joins (stage->vmcnt(0)->
// s_barrier, lgkm waits) where every resident wave stalls together.
// This round: DELETE THE LDS PIPELINE. K=64 -> MFMA frags are directly
// loadable from global, coalesced (16 rows x 64 B per instr), L2-resident
// (xnb = 2 MB per XCD). Per wave per pair: 16 global_load_dwordx4 with
// SGPR-base + 32-bit per-lane offsets (near-zero addressing VALU), 32 MFMA,
// epilogue — waves fully independent, ONE __syncthreads (red combine) per
// block, LDS 2 KB. Occupancy VGPR-bound ~3 waves/SIMD = 12 waves/CU (at the
// knee). L2 traffic 528 MB ~= 15 us, hidden under the 26 us VALU shadow.
// Per-element math byte-identical to r13/r16 (128x128 pair shapes).
// Success: den 33-38 us, VALUBusy >=70, LDS_Block ~2KB, total 86-92.
// Failure A: den ~46, VALUBusy 40-50 -> L2 latency not hidden -> prefetch
//            next pair's frags (no barriers to fight now).
// Failure B: den >46, VALUBusy >60 -> addressing overhead -> disasm saddr.
// Failure C: wrong result -> revert r14.

#define NROWS 16384
#define KDIM 64
#define NTILE 128
#define NTB (NROWS / NTILE)          // 128 tile-blocks per side
#define NPAIRS (NTB * (NTB + 1) / 2) // 8256 upper-triangle tile pairs

typedef __attribute__((ext_vector_type(8))) short short8;   // 8 bf16 = 4 VGPRs
typedef __attribute__((ext_vector_type(4))) float f32x4;
typedef __attribute__((ext_vector_type(2))) float f32x2;

__device__ __forceinline__ float exp2_fast(float x) {
#if __has_builtin(__builtin_amdgcn_exp2f)
    return __builtin_amdgcn_exp2f(x);   // bare v_exp_f32
#else
    return exp2f(x);
#endif
}

// ---- kernel A: row-normalize, prescale by sqrt(2*log2e) -> bf16 -----------
// 64 rows/block, 4 lanes/row, 16 floats/thread. Also zeroes ctrl/accum.
__global__ __launch_bounds__(256) void normalize_kernel(const float* __restrict__ x,
                                                        unsigned short* __restrict__ xnb,
                                                        unsigned int* __restrict__ ctrl,
                                                        float* __restrict__ accum) {
    const int t = threadIdx.x;
    const int r = blockIdx.x * 64 + (t >> 2);
    const int q = t & 3;
    const float4* xr = (const float4*)(x + (size_t)r * KDIM) + q * 4;
    const float4 v0 = xr[0], v1 = xr[1], v2 = xr[2], v3 = xr[3];
    float ss = v0.x * v0.x + v0.y * v0.y + v0.z * v0.z + v0.w * v0.w
             + v1.x * v1.x + v1.y * v1.y + v1.z * v1.z + v1.w * v1.w
             + v2.x * v2.x + v2.y * v2.y + v2.z * v2.z + v2.w * v2.w
             + v3.x * v3.x + v3.y * v3.y + v3.z * v3.z + v3.w * v3.w;
    ss += __shfl_xor(ss, 1, 64);
    ss += __shfl_xor(ss, 2, 64);
    // sqrt(2*log2(e)) = sqrt(2.88539008) = 1.69864404
    const float a = 1.69864404f * rsqrtf(fmaxf(ss, 1e-16f));
    const float vals[16] = {v0.x * a, v0.y * a, v0.z * a, v0.w * a,
                            v1.x * a, v1.y * a, v1.z * a, v1.w * a,
                            v2.x * a, v2.y * a, v2.z * a, v2.w * a,
                            v3.x * a, v3.y * a, v3.z * a, v3.w * a};
    union { unsigned short us[16]; uint4 v[2]; } o;
    #pragma unroll
    for (int k = 0; k < 16; k++) {
        __hip_bfloat16 b = __float2bfloat16(vals[k]);
        o.us[k] = *(unsigned short*)&b;
    }
    uint4* dst = (uint4*)(xnb + (size_t)r * KDIM);
    dst[q * 2] = o.v[0];
    dst[q * 2 + 1] = o.v[1];
    if (blockIdx.x == 0 && t == 0) { ctrl[0] = 0u; ctrl[1] = 0u; accum[0] = 0.0f; }
}

// ---- kernel B: LDS-free 128x128 tile-pair partial sums --------------------
// Block = upper-triangle tile pair (ti<=tj), one-shot, 8256 blocks, 4 waves
// 2x2, 64x64/wave, mfma_f32_16x16x32_bf16 (A-frag: lane m=l&15 holds
// k=(l>>4)*8+e; C/D: col=l&15, row=(l>>4)*4+reg). Fragments loaded DIRECTLY
// from global (no LDS staging, no staging barriers): frag(kc,it) is 16 B/lane
// at xnb[(tilebase + wy*64 + it*16 + m)*64 + (kc*4+p)*8] — per instr the wave
// touches 16 rows x 64 B = coalesced, L2-resident. Only LDS use: 2 KB red.
__global__ __launch_bounds__(256) void den_kernel(const unsigned short* __restrict__ xnb,
                                                  float* __restrict__ S,
                                                  float* __restrict__ num) {
    __shared__ float red[512];     // 2 KB cross-wave combine scratch

    const int t = threadIdx.x;
    const int bt = blockIdx.x;
    // triangular decode (f32; loops absorb rounding): bt -> (ti, tj)
    int ti = (int)((257.0f - sqrtf(66049.0f - 8.0f * (float)bt)) * 0.5f);
    while (ti * NTB - ti * (ti - 1) / 2 > bt) ti--;
    while ((ti + 1) * NTB - (ti + 1) * ti / 2 <= bt) ti++;
    const int tj = ti + (bt - (ti * NTB - ti * (ti - 1) / 2));
    const int ib = ti * NTILE, jb = tj * NTILE;
    const bool diag = (ti == tj);

    const int lane = t & 63, w = t >> 6;
    const int wi = w >> 1, wj = w & 1;
    const int m = lane & 15, p = lane >> 4;

    const f32x4 zero = {0.f, 0.f, 0.f, 0.f};
    f32x4 acc[4][4];
    #pragma unroll
    for (int it = 0; it < 4; it++)
        #pragma unroll
        for (int jt = 0; jt < 4; jt++) acc[it][jt] = zero;

    // per-lane element offsets (32-bit; xnb is 1 Mi elements): base rows
    const int arow = ib + wi * 64 + m;   // + it*16
    const int brow = jb + wj * 64 + m;
    const int kofs = p * 8;              // + kc*32

    #pragma unroll
    for (int kc = 0; kc < 2; kc++) {
        short8 af[4], bf[4];
        const int ko = kc * 32 + kofs;
        #pragma unroll
        for (int it = 0; it < 4; it++) {
            af[it] = *(const short8*)(xnb + (arow + it * 16) * KDIM + ko);
            bf[it] = *(const short8*)(xnb + (brow + it * 16) * KDIM + ko);
        }
        #pragma unroll
        for (int it = 0; it < 4; it++)
            #pragma unroll
            for (int jt = 0; jt < 4; jt++)
                acc[it][jt] = __builtin_amdgcn_mfma_f32_16x16x32_bf16(af[it], bf[jt], acc[it][jt], 0, 0, 0);
    }

    // epilogue: exp2; packed (v_pk_add_f32) accumulation of col/row partials
    f32x2 cs01 = {0.f, 0.f}, cs23 = {0.f, 0.f};
    float rs[16];
    #pragma unroll
    for (int it = 0; it < 4; it++) {
        #pragma unroll
        for (int reg = 0; reg < 4; reg++) {
            f32x2 e01, e23;
            e01.x = exp2_fast(acc[it][0][reg]);
            e01.y = exp2_fast(acc[it][1][reg]);
            e23.x = exp2_fast(acc[it][2][reg]);
            e23.y = exp2_fast(acc[it][3][reg]);
            cs01 += e01;
            cs23 += e23;
            const f32x2 rp = e01 + e23;
            rs[it * 4 + reg] = rp.x + rp.y;
        }
    }
    float cs[4] = {cs01.x, cs01.y, cs23.x, cs23.y};

    // colsum butterfly over p (value-halving): lane ends with column p*16+m
    {
        const bool hb = (p & 2) != 0;
        float s0 = hb ? cs[0] : cs[2], k0 = hb ? cs[2] : cs[0];
        float s1 = hb ? cs[1] : cs[3], k1 = hb ? cs[3] : cs[1];
        cs[0] = k0 + __shfl_xor(s0, 32, 64);
        cs[1] = k1 + __shfl_xor(s1, 32, 64);
        const bool lb = (p & 1) != 0;
        float s2 = lb ? cs[0] : cs[1], k2 = lb ? cs[1] : cs[0];
        cs[0] = k2 + __shfl_xor(s2, 16, 64);
    }

    // rowsum butterfly over m (value-halving, 15 shfl): lane ends with row
    // (m>>2)*16 + p*4 + (m&3)
    if (!diag) {
        #pragma unroll
        for (int k = 0; k < 8; k++) {
            const float snd = (m & 8) ? rs[k] : rs[k + 8];
            const float kp  = (m & 8) ? rs[k + 8] : rs[k];
            rs[k] = kp + __shfl_xor(snd, 8, 64);
        }
        #pragma unroll
        for (int k = 0; k < 4; k++) {
            const float snd = (m & 4) ? rs[k] : rs[k + 4];
            const float kp  = (m & 4) ? rs[k + 4] : rs[k];
            rs[k] = kp + __shfl_xor(snd, 4, 64);
        }
        #pragma unroll
        for (int k = 0; k < 2; k++) {
            const float snd = (m & 2) ? rs[k] : rs[k + 2];
            const float kp  = (m & 2) ? rs[k + 2] : rs[k];
            rs[k] = kp + __shfl_xor(snd, 2, 64);
        }
        {
            const float snd = (m & 1) ? rs[0] : rs[1];
            const float kp  = (m & 1) ? rs[1] : rs[0];
            rs[0] = kp + __shfl_xor(snd, 1, 64);
        }
    } else if (wi == wj) {
        // num[j] = exp2(acc(row j^1, col j)) from the diagonal tile: element
        // (m^1, m) of sub-tile it lives in lane ((m^1)>>2, m), reg (m^1)&3.
        const int pc = m ^ 1;
        if ((pc >> 2) == p) {
            #pragma unroll
            for (int it = 0; it < 4; it++)
                num[jb + wj * 64 + it * 16 + m] = exp2_fast(acc[it][it][pc & 3]);
        }
    }

    // cross-wave combine through red (one-shot block: single barrier)
    red[wi * 128 + wj * 64 + p * 16 + m] = cs[0];
    if (!diag) red[256 + wj * 128 + wi * 64 + ((m >> 2) * 16 + p * 4 + (m & 3))] = rs[0];
    __syncthreads();

    // exactly-once coalesced partial stores (no atomics, no fences):
    //   colsums -> S[tj][ti][c] (den[jb+c]); rowsums -> S[ti][tj][r] (den[ib+r])
    if (t < NTILE) {
        S[((size_t)tj * NTB + ti) * NTILE + t] = red[t] + red[128 + t];
    } else if (!diag) {
        const int u = t - NTILE;
        S[((size_t)ti * NTB + tj) * NTILE + u] = red[256 + u] + red[256 + 128 + u];
    }
}

// ---- kernel C: den[a*128+c] = sum_b S[a][b][c]; ratio + global sum + log ---
// 128 blocks; ticket write of the final scalar (r6-verified).
__global__ __launch_bounds__(256) void reduce_kernel(const float* __restrict__ S,
                                                     const float* __restrict__ num,
                                                     unsigned int* __restrict__ ctrl,
                                                     float* __restrict__ accum,
                                                     float* __restrict__ out) {
    const int a = blockIdx.x;
    const int t = threadIdx.x;
    const int c = t & 127, h = t >> 7;     // h splits the b-range in two
    const float* base = S + (size_t)a * (NTB * NTILE) + (size_t)h * 64 * NTILE + c;
    float s = 0.0f;
    #pragma unroll 8
    for (int b = 0; b < 64; b++) s += base[(size_t)b * NTILE];

    __shared__ float part[NTILE];
    __shared__ float wsum[4];
    if (h == 0) part[c] = s;
    __syncthreads();

    float r = 0.0f;
    if (h == 1) {
        const float E2 = 7.38905609893065f;  // exp(1/T)=exp(2): diagonal removal
        r = num[a * NTILE + c] / ((part[c] + s) - E2);
    }
    #pragma unroll
    for (int o = 32; o > 0; o >>= 1) r += __shfl_xor(r, o, 64);
    if ((t & 63) == 0) wsum[t >> 6] = r;
    __syncthreads();
    if (t == 0) {
        const float bsum = (wsum[0] + wsum[1]) + (wsum[2] + wsum[3]);
        __hip_atomic_fetch_add(accum, bsum, __ATOMIC_RELAXED, __HIP_MEMORY_SCOPE_AGENT);
        const unsigned int tk = __hip_atomic_fetch_add(&ctrl[1], 1u, __ATOMIC_ACQ_REL, __HIP_MEMORY_SCOPE_AGENT);
        if (tk == (unsigned)(NTB - 1)) {   // last block writes the loss
            const float total = __hip_atomic_load(accum, __ATOMIC_ACQUIRE, __HIP_MEMORY_SCOPE_AGENT);
            out[0] = -logf(total / (float)NROWS);
        }
    }
}

extern "C" void kernel_launch(void* const* d_in, const int* in_sizes, int n_in,
                              void* d_out, int out_size, void* d_ws, size_t ws_size,
                              hipStream_t stream) {
    const float* x = (const float*)d_in[0];
    float* out = (float*)d_out;

    // ws: xnb [2 MB bf16] | num [64 KB f32] | accum [1 f32] | ctrl [2 u32] | S [8 MB f32]
    unsigned short* xnb = (unsigned short*)d_ws;
    float* num = (float*)((char*)d_ws + (size_t)NROWS * KDIM * sizeof(unsigned short));
    float* accum = num + NROWS;
    unsigned int* ctrl = (unsigned int*)(accum + 1);
    float* S = (float*)(ctrl + 2);

    normalize_kernel<<<NROWS / 64, 256, 0, stream>>>(x, xnb, ctrl, accum);
    den_kernel<<<NPAIRS, 256, 0, stream>>>(xnb, S, num);
    reduce_kernel<<<NTB, 256, 0, stream>>>(S, num, ctrl, accum, out);
}

// Round 8
// 98.509 us; speedup vs baseline: 1.3308x; 1.3308x over previous
//
#include <hip/hip_runtime.h>
#include <hip/hip_bf16.h>
#include <math.h>

// Contrastive (NT-Xent-like) loss over x[16384][64] fp32.
//   x_hat = sqrt(2*log2e) * x / ||x||   (so exp(sim/T) = exp2(x_hat_i.x_hat_j))
//   den[j] = sum_i exp2(x_hat_i . x_hat_j) - e^2
//   num[j] = exp2(x_hat_{j^1} . x_hat_j)
//   out = -log( mean_j num[j] / den[j] )
//
// Round 22: r21 post-mortem — LDS-free direct loads are 16-line scatters
// (stride-128B rows): TA-serialized, den 72.6 despite 28% occupancy. Lesson:
// coalesced global->LDS staging is mandatory; >12 waves/CU buys nothing.
// Ledger: one-shot+LDS 45.8 | +occ 44.4 | persistent-dbuf 48 | pipeline spill
// | 256^2-quadrant 57 (occ loss) | LDS-free 72 (latency). r13 shape optimal.
// This round: A-REUSE x2 within r13's constraints (<=52KB LDS, <=170 VGPR,
// 128x128 passes, one 64-reg acc reused). Block = (A-tile ti) x (B-tiles
// 2g, 2g+1): 4160 blocks, 2 pairs each. Staging/pair 2->1.5 tiles,
// barriers/pair 2->1, rowsum butterfly + row-store/pair 1->0.5 (rs
// accumulates across both B-tiles; merged row write to S[ti][tj2] + zero
// fill of S[ti][tj1] keeps reduce's sum-over-b exact; slot coverage proof
// in comments below). Per-element math byte-identical to r13.
// Success: den 38-43, LDS ~52KB, VGPR 140-160, total 91-96.
// Failure A: wrong result -> decode/slot bug -> revert r14.
// Failure B: den >=45 -> plateau is structural -> revert r14, declare.
// Failure C: WRITE >>50MB -> spill -> un-merge.

#define NROWS 16384
#define KDIM 64
#define NTILE 128
#define NTB (NROWS / NTILE)     // 128 tile-blocks per side
#define NGRP (NTB / 2)          // 64 B-tile groups {2g, 2g+1}
#define NBLOCKS (NGRP * (NGRP + 1))  // sum_g (2g+2) = 4160 blocks

typedef __attribute__((ext_vector_type(8))) short short8;   // 8 bf16 = 4 VGPRs
typedef __attribute__((ext_vector_type(4))) float f32x4;
typedef __attribute__((ext_vector_type(2))) float f32x2;

__device__ __forceinline__ float exp2_fast(float x) {
#if __has_builtin(__builtin_amdgcn_exp2f)
    return __builtin_amdgcn_exp2f(x);   // bare v_exp_f32
#else
    return exp2f(x);
#endif
}

// async global->LDS DMA, 16 B per lane; LDS side must be uniform + lane*16.
__device__ __forceinline__ void load_lds16(const void* g, void* l) {
    __builtin_amdgcn_global_load_lds((const __attribute__((address_space(1))) unsigned int*)g,
                                     (__attribute__((address_space(3))) unsigned int*)l,
                                     16, 0, 0);
}

// ---- kernel A: row-normalize, prescale by sqrt(2*log2e) -> bf16 -----------
// 64 rows/block, 4 lanes/row, 16 floats/thread. Also zeroes ctrl/accum.
__global__ __launch_bounds__(256) void normalize_kernel(const float* __restrict__ x,
                                                        unsigned short* __restrict__ xnb,
                                                        unsigned int* __restrict__ ctrl,
                                                        float* __restrict__ accum) {
    const int t = threadIdx.x;
    const int r = blockIdx.x * 64 + (t >> 2);
    const int q = t & 3;
    const float4* xr = (const float4*)(x + (size_t)r * KDIM) + q * 4;
    const float4 v0 = xr[0], v1 = xr[1], v2 = xr[2], v3 = xr[3];
    float ss = v0.x * v0.x + v0.y * v0.y + v0.z * v0.z + v0.w * v0.w
             + v1.x * v1.x + v1.y * v1.y + v1.z * v1.z + v1.w * v1.w
             + v2.x * v2.x + v2.y * v2.y + v2.z * v2.z + v2.w * v2.w
             + v3.x * v3.x + v3.y * v3.y + v3.z * v3.z + v3.w * v3.w;
    ss += __shfl_xor(ss, 1, 64);
    ss += __shfl_xor(ss, 2, 64);
    // sqrt(2*log2(e)) = sqrt(2.88539008) = 1.69864404
    const float a = 1.69864404f * rsqrtf(fmaxf(ss, 1e-16f));
    const float vals[16] = {v0.x * a, v0.y * a, v0.z * a, v0.w * a,
                            v1.x * a, v1.y * a, v1.z * a, v1.w * a,
                            v2.x * a, v2.y * a, v2.z * a, v2.w * a,
                            v3.x * a, v3.y * a, v3.z * a, v3.w * a};
    union { unsigned short us[16]; uint4 v[2]; } o;
    #pragma unroll
    for (int k = 0; k < 16; k++) {
        __hip_bfloat16 b = __float2bfloat16(vals[k]);
        o.us[k] = *(unsigned short*)&b;
    }
    uint4* dst = (uint4*)(xnb + (size_t)r * KDIM);
    dst[q * 2] = o.v[0];
    dst[q * 2 + 1] = o.v[1];
    if (blockIdx.x == 0 && t == 0) { ctrl[0] = 0u; ctrl[1] = 0u; accum[0] = 0.0f; }
}

// One 128x128 pair pass: 32 MFMA + exp2 epilogue + colsum butterfly + red
// write; rs accumulation gated by DOROW. Macro (not function) so rs/acc stay
// in registers with static indices (rule #20: no address-taken arrays).
#define PAIR_PASS(BSPTR, JB, DIAGX, DOROW, REDBASE) do {                       \
    f32x4 acc[4][4];                                                           \
    _Pragma("unroll")                                                          \
    for (int it = 0; it < 4; it++)                                             \
        _Pragma("unroll")                                                      \
        for (int jt = 0; jt < 4; jt++) acc[it][jt] = zero;                     \
    _Pragma("unroll")                                                          \
    for (int kc = 0; kc < 2; kc++) {                                           \
        short8 af[4], bf[4];                                                   \
        const int qx = ((kc << 2) | p) ^ (m & 7);                              \
        _Pragma("unroll")                                                      \
        for (int it = 0; it < 4; it++) {                                       \
            af[it] = *(const short8*)(As + ((wi * 64 + it * 16 + m) * 8 + qx) * 8);      \
            bf[it] = *(const short8*)((BSPTR) + ((wj * 64 + it * 16 + m) * 8 + qx) * 8); \
        }                                                                      \
        _Pragma("unroll")                                                      \
        for (int it = 0; it < 4; it++)                                         \
            _Pragma("unroll")                                                  \
            for (int jt = 0; jt < 4; jt++)                                     \
                acc[it][jt] = __builtin_amdgcn_mfma_f32_16x16x32_bf16(af[it], bf[jt], acc[it][jt], 0, 0, 0); \
    }                                                                          \
    f32x2 cs01 = {0.f, 0.f}, cs23 = {0.f, 0.f};                                \
    _Pragma("unroll")                                                          \
    for (int it = 0; it < 4; it++) {                                           \
        _Pragma("unroll")                                                      \
        for (int reg = 0; reg < 4; reg++) {                                    \
            f32x2 e01, e23;                                                    \
            e01.x = exp2_fast(acc[it][0][reg]);                                \
            e01.y = exp2_fast(acc[it][1][reg]);                                \
            e23.x = exp2_fast(acc[it][2][reg]);                                \
            e23.y = exp2_fast(acc[it][3][reg]);                                \
            cs01 += e01;                                                       \
            cs23 += e23;                                                       \
            if (DOROW) {                                                       \
                const f32x2 rp = e01 + e23;                                    \
                rs[it * 4 + reg] += rp.x + rp.y;                               \
            }                                                                  \
        }                                                                      \
    }                                                                          \
    if ((DIAGX) && wi == wj) {                                                 \
        const int pc = m ^ 1;                                                  \
        if ((pc >> 2) == p) {                                                  \
            _Pragma("unroll")                                                  \
            for (int it = 0; it < 4; it++)                                     \
                num[(JB) + wj * 64 + it * 16 + m] = exp2_fast(acc[it][it][pc & 3]); \
        }                                                                      \
    }                                                                          \
    {                                                                          \
        float cs[4] = {cs01.x, cs01.y, cs23.x, cs23.y};                        \
        const bool hb = (p & 2) != 0;                                          \
        float s0 = hb ? cs[0] : cs[2], k0 = hb ? cs[2] : cs[0];                \
        float s1 = hb ? cs[1] : cs[3], k1 = hb ? cs[3] : cs[1];                \
        cs[0] = k0 + __shfl_xor(s0, 32, 64);                                   \
        cs[1] = k1 + __shfl_xor(s1, 32, 64);                                   \
        const bool lb = (p & 1) != 0;                                          \
        float s2 = lb ? cs[0] : cs[1], k2 = lb ? cs[1] : cs[0];                \
        cs[0] = k2 + __shfl_xor(s2, 16, 64);                                   \
        red[(REDBASE) + wi * 128 + wj * 64 + p * 16 + m] = cs[0];              \
    }                                                                          \
} while (0)

// ---- kernel B: A-tile x {2 B-tiles} partial sums --------------------------
// Block (ti, g): pairs (ti, 2g) [iff ti<=2g] and (ti, 2g+1) [always; ti<=2g+1
// by decode]. 4 waves 2x2, 64x64/wave, mfma_f32_16x16x32_bf16 (r3-r13 layout,
// XOR-swizzled staging, 0 bank conflicts). rs accumulates across both passes;
// merged row write -> S[ti][2g+1], zero -> S[ti][2g] (iff ti<2g).
// Slot coverage (each S[a][b] written exactly once):
//   col even  S[2g][ti']  : block (ti',g) pass1 (ti'<=2g == havePair1)
//   col odd   S[2g+1][ti']: block (ti',g) pass2
//   row odd   S[ti][2g+1] : block (ti,g) merged row (requires ti<2g+1 <=> !diag2)
//   row even  S[ti][2g]   : block (ti,g) zero-fill (requires ti<2g)
__global__ __launch_bounds__(256) void den_kernel(const unsigned short* __restrict__ xnb,
                                                  float* __restrict__ S,
                                                  float* __restrict__ num) {
    __shared__ float4 Abuf[1024];   // 16 KB
    __shared__ float4 B1buf[1024];  // 16 KB
    __shared__ float4 B2buf[1024];  // 16 KB
    __shared__ float red[768];      // 3 KB: [0,256) col1, [256,512) col2, [512,768) row

    const int t = threadIdx.x;
    const int bt = blockIdx.x;
    // decode: cumulative before group g is g*(g+1); ti in [0, 2g+2)
    int gj = (int)((sqrtf(4.0f * (float)bt + 1.0f) - 1.0f) * 0.5f);
    while (gj * (gj + 1) > bt) gj--;
    while ((gj + 1) * (gj + 2) <= bt) gj++;
    const int ti = bt - gj * (gj + 1);
    const int tj1 = 2 * gj, tj2 = 2 * gj + 1;
    const bool havePair1 = (ti <= tj1);
    const bool diag1 = (ti == tj1), diag2 = (ti == tj2);
    const int ib = ti * NTILE;

    // staging: chunk c -> row r=c>>3, k-chunk q=(c&7)^(r&7). Global side is a
    // per-lane VGPR address (swizzle allowed); LDS side is uniform + lane*16.
    #pragma unroll
    for (int s = 0; s < 4; s++) {
        const int c = s * 256 + t;
        const int r = c >> 3;
        const int q = ((c & 7) ^ (r & 7)) * 8;
        load_lds16(xnb + (size_t)(ib + r) * KDIM + q, &Abuf[c]);
        load_lds16(xnb + (size_t)(tj1 * NTILE + r) * KDIM + q, &B1buf[c]);
        load_lds16(xnb + (size_t)(tj2 * NTILE + r) * KDIM + q, &B2buf[c]);
    }
    __syncthreads();   // compiler drains vmcnt before s_barrier (covers DMA)

    const int lane = t & 63, w = t >> 6;
    const int wi = w >> 1, wj = w & 1;
    const int m = lane & 15, p = lane >> 4;

    const f32x4 zero = {0.f, 0.f, 0.f, 0.f};
    const unsigned short* As = (const unsigned short*)Abuf;
    const unsigned short* Bs1 = (const unsigned short*)B1buf;
    const unsigned short* Bs2 = (const unsigned short*)B2buf;

    float rs[16];   // row partials, accumulated across both passes
    #pragma unroll
    for (int k = 0; k < 16; k++) rs[k] = 0.f;

    if (havePair1) PAIR_PASS(Bs1, tj1 * NTILE, diag1, !diag1, 0);
    PAIR_PASS(Bs2, tj2 * NTILE, diag2, !diag2, 256);

    // merged rowsum butterfly (value-halving over m, 15 shfl): lane ends with
    // row (m>>2)*16 + p*4 + (m&3)
    if (!diag2) {
        #pragma unroll
        for (int k = 0; k < 8; k++) {
            const float snd = (m & 8) ? rs[k] : rs[k + 8];
            const float kp  = (m & 8) ? rs[k + 8] : rs[k];
            rs[k] = kp + __shfl_xor(snd, 8, 64);
        }
        #pragma unroll
        for (int k = 0; k < 4; k++) {
            const float snd = (m & 4) ? rs[k] : rs[k + 4];
            const float kp  = (m & 4) ? rs[k + 4] : rs[k];
            rs[k] = kp + __shfl_xor(snd, 4, 64);
        }
        #pragma unroll
        for (int k = 0; k < 2; k++) {
            const float snd = (m & 2) ? rs[k] : rs[k + 2];
            const float kp  = (m & 2) ? rs[k + 2] : rs[k];
            rs[k] = kp + __shfl_xor(snd, 2, 64);
        }
        {
            const float snd = (m & 1) ? rs[0] : rs[1];
            const float kp  = (m & 1) ? rs[1] : rs[0];
            rs[0] = kp + __shfl_xor(snd, 1, 64);
        }
        red[512 + wj * 128 + wi * 64 + ((m >> 2) * 16 + p * 4 + (m & 3))] = rs[0];
    }
    __syncthreads();

    // exactly-once coalesced partial stores (coverage proof in header):
    if (t < NTILE) {
        if (havePair1)
            S[((size_t)tj1 * NTB + ti) * NTILE + t] = red[t] + red[128 + t];
        S[((size_t)tj2 * NTB + ti) * NTILE + t] = red[256 + t] + red[384 + t];
    } else {
        const int u = t - NTILE;
        if (!diag2)
            S[((size_t)ti * NTB + tj2) * NTILE + u] = red[512 + u] + red[640 + u];
        if (ti < tj1)
            S[((size_t)ti * NTB + tj1) * NTILE + u] = 0.0f;
    }
}

// ---- kernel C: den[a*128+c] = sum_b S[a][b][c]; ratio + global sum + log ---
// 128 blocks; ticket write of the final scalar (r6-verified).
__global__ __launch_bounds__(256) void reduce_kernel(const float* __restrict__ S,
                                                     const float* __restrict__ num,
                                                     unsigned int* __restrict__ ctrl,
                                                     float* __restrict__ accum,
                                                     float* __restrict__ out) {
    const int a = blockIdx.x;
    const int t = threadIdx.x;
    const int c = t & 127, h = t >> 7;     // h splits the b-range in two
    const float* base = S + (size_t)a * (NTB * NTILE) + (size_t)h * 64 * NTILE + c;
    float s = 0.0f;
    #pragma unroll 8
    for (int b = 0; b < 64; b++) s += base[(size_t)b * NTILE];

    __shared__ float part[NTILE];
    __shared__ float wsum[4];
    if (h == 0) part[c] = s;
    __syncthreads();

    float r = 0.0f;
    if (h == 1) {
        const float E2 = 7.38905609893065f;  // exp(1/T)=exp(2): diagonal removal
        r = num[a * NTILE + c] / ((part[c] + s) - E2);
    }
    #pragma unroll
    for (int o = 32; o > 0; o >>= 1) r += __shfl_xor(r, o, 64);
    if ((t & 63) == 0) wsum[t >> 6] = r;
    __syncthreads();
    if (t == 0) {
        const float bsum = (wsum[0] + wsum[1]) + (wsum[2] + wsum[3]);
        __hip_atomic_fetch_add(accum, bsum, __ATOMIC_RELAXED, __HIP_MEMORY_SCOPE_AGENT);
        const unsigned int tk = __hip_atomic_fetch_add(&ctrl[1], 1u, __ATOMIC_ACQ_REL, __HIP_MEMORY_SCOPE_AGENT);
        if (tk == (unsigned)(NTB - 1)) {   // last block writes the loss
            const float total = __hip_atomic_load(accum, __ATOMIC_ACQUIRE, __HIP_MEMORY_SCOPE_AGENT);
            out[0] = -logf(total / (float)NROWS);
        }
    }
}

extern "C" void kernel_launch(void* const* d_in, const int* in_sizes, int n_in,
                              void* d_out, int out_size, void* d_ws, size_t ws_size,
                              hipStream_t stream) {
    const float* x = (const float*)d_in[0];
    float* out = (float*)d_out;

    // ws: xnb [2 MB bf16] | num [64 KB f32] | accum [1 f32] | ctrl [2 u32] | S [8 MB f32]
    unsigned short* xnb = (unsigned short*)d_ws;
    float* num = (float*)((char*)d_ws + (size_t)NROWS * KDIM * sizeof(unsigned short));
    float* accum = num + NROWS;
    unsigned int* ctrl = (unsigned int*)(accum + 1);
    float* S = (float*)(ctrl + 2);

    normalize_kernel<<<NROWS / 64, 256, 0, stream>>>(x, xnb, ctrl, accum);
    den_kernel<<<NBLOCKS, 256, 0, stream>>>(xnb, S, num);
    reduce_kernel<<<NTB, 256, 0, stream>>>(S, num, ctrl, accum, out);
}